// Round 5
// baseline (142.768 us; speedup 1.0000x reference)
//
#include <hip/hip_runtime.h>
#include <stdint.h>

typedef __bf16 bf16x8 __attribute__((ext_vector_type(8)));
typedef __bf16 bf16x4v __attribute__((ext_vector_type(4)));
typedef float f32x4 __attribute__((ext_vector_type(4)));

#define TOK 49
#define CDIM 192
#define NHEAD 6
#define THREADS 768
#define QKSCALE 0.17677669529663687f

// LDS (75776 B total -> 2 blocks/CU):
// X region @0      (24576): ph1-2: x [64][192] bf16 stride 384B swzA
//                           ph3: per-wave scratch [32][32]swzQ (q transpose), then P0 [16][64]swzA
//                           late ph3 + ph4: attn_o [64][192] swzA
// K region @24576  (24576): ph2-3a: k 6x[64][32] swzQ; ph3b: P1 per-wave [16][64] swzA @ KOFF+wave*2048
// V region @49152  (24576): vT 6x[32][64] stride 128B swzA
// ones    @73728  (2048):   [16][64] stride 128B, row0 = 1.0, rows 1-15 = 0 (shared sum column)
#define XOFF   0u
#define KOFF   24576u
#define VOFF   49152u
#define ONESOFF 73728u
#define SMEM_BYTES 75776u

__device__ __forceinline__ unsigned short f2bf(float f) {
  unsigned u = __float_as_uint(f);
  return (unsigned short)((u + 0x7fffu + ((u >> 16) & 1u)) >> 16);  // RNE (host-pack kernels only)
}
// XOR-swizzle byte-in-row for stride%128==0 tiles (bits 4-6)
__device__ __forceinline__ uint32_t swzA(uint32_t row, uint32_t b) { return b ^ ((row & 7u) << 4); }
// XOR-swizzle for stride-64B tiles (bits 4-5)
__device__ __forceinline__ uint32_t swzQ(uint32_t row, uint32_t b) { return b ^ (((row >> 1) & 3u) << 4); }

// Pack fp32 weight matrix [192][NT*16] row-major into bf16 MFMA B-fragments:
// frag (nt, ks): lane l gets B[ks*32 + (l>>4)*8 + j][nt*16 + (l&15)], j=0..7, stored
// contiguously at ((nt*6+ks)*64 + l)*8 bf16. Columns nt < nscale are pre-multiplied by scale.
__global__ void wa_pack_w(const float* __restrict__ w, unsigned short* __restrict__ outp,
                          int NT, int ncols, int nscale, float scale) {
  int idx = blockIdx.x * blockDim.x + threadIdx.x;
  if (idx >= NT * 6 * 64) return;
  int l = idx & 63;
  int frag = idx >> 6;
  int ks = frag % 6;
  int nt = frag / 6;
  float sc = (nt < nscale) ? scale : 1.0f;
  int n = nt * 16 + (l & 15);
  int k0 = ks * 32 + ((l >> 4) << 3);
  unsigned short v[8];
#pragma unroll
  for (int j = 0; j < 8; ++j) v[j] = f2bf(w[(k0 + j) * ncols + n] * sc);
  ushort4* dst = reinterpret_cast<ushort4*>(outp + (size_t)idx * 8);
  dst[0] = make_ushort4(v[0], v[1], v[2], v[3]);
  dst[1] = make_ushort4(v[4], v[5], v[6], v[7]);
}

// Precompute relative-position bias in MFMA C-fragment layout:
// out[((head*4 + mtile)*4 + nt)*64 + lane][r] = bias(row=mtile*16+(lane>>4)*4+r, col=nt*16+(lane&15))
// with -1e30 for masked (row>=49 || col>=49) entries so softmax masking is free.
__global__ void wa_pack_bias(const float* __restrict__ rpb, float* __restrict__ outb) {
  int idx = blockIdx.x * blockDim.x + threadIdx.x;
  if (idx >= NHEAD * 4 * 4 * 64) return;
  int lane = idx & 63;
  int nt = (idx >> 6) & 3;
  int mtile = (idx >> 8) & 3;
  int head = idx >> 10;
  int col = nt * 16 + (lane & 15);
  int row0 = mtile * 16 + ((lane >> 4) << 2);
  float4 v;
  float* vp = reinterpret_cast<float*>(&v);
#pragma unroll
  for (int r = 0; r < 4; ++r) {
    int row = row0 + r;
    float val = -1e30f;
    if (row < TOK && col < TOK) {
      int ri = (row / 7 - col / 7 + 6) * 13 + (row % 7 - col % 7 + 6);
      val = rpb[ri * NHEAD + head];
    }
    vp[r] = val;
  }
  *reinterpret_cast<float4*>(outb + (size_t)idx * 4) = v;
}

__global__ __launch_bounds__(THREADS, 6) void wa_main(
    const float* __restrict__ x,
    const float* __restrict__ qkv_b,
    const float* __restrict__ proj_b,
    const float* __restrict__ bias_c,          // C-fragment-layout bias table
    const unsigned short* __restrict__ wqkv,   // packed 36 ntiles (q cols pre-scaled)
    const unsigned short* __restrict__ wproj,  // packed 12 ntiles
    float* __restrict__ out) {
  extern __shared__ __align__(16) char smem[];
  const int tid = threadIdx.x;
  const int lane = tid & 63;
  const int wave = __builtin_amdgcn_readfirstlane(tid >> 6);  // wave-uniform -> SGPR
  const int l15 = lane & 15;
  const int g16 = (lane >> 4) << 4;   // byte offset of this lane-group's 16B k-slice
  const int rloc0 = (lane >> 4) << 2;
  const int b = blockIdx.x;
  const float* xg = x + (size_t)b * (TOK * CDIM);
  const int h = wave >> 1;            // head for q/attention phases
  const int mbase = (wave & 1) << 1;  // first of 2 owned q m-tiles

  // ---- Phase 1: x -> LDS bf16 [64][192] (rows 49..63 zero); ones tile fill ----
  for (int c = tid; c < 64 * 48; c += THREADS) {
    int r = c / 48;
    int cc = (c % 48) * 4;
    uint32_t addr = XOFF + (uint32_t)r * 384u + swzA((uint32_t)r, (uint32_t)(cc * 2));
    bf16x4v hv;
    if (r < TOK) {
      const float4 v = *reinterpret_cast<const float4*>(xg + r * CDIM + cc);
      hv = (bf16x4v){(__bf16)v.x, (__bf16)v.y, (__bf16)v.z, (__bf16)v.w};
    } else {
      hv = (bf16x4v){(__bf16)0.f, (__bf16)0.f, (__bf16)0.f, (__bf16)0.f};
    }
    *reinterpret_cast<bf16x4v*>(smem + addr) = hv;
  }
  if (tid < 128) {
    // ones tile: 2048B = 128 x 16B. Row 0 (first 8 stores) = bf16(1.0), rest 0.
    uint4 fill = (tid < 8) ? make_uint4(0x3F803F80u, 0x3F803F80u, 0x3F803F80u, 0x3F803F80u)
                           : make_uint4(0u, 0u, 0u, 0u);
    *reinterpret_cast<uint4*>(smem + ONESOFF + (uint32_t)tid * 16u) = fill;
  }
  __syncthreads();

  // ---- Phase 2a: k (waves 0-5) or v (waves 6-11): 2 ntiles x 4 mtiles -> LDS ----
  // Split into two 2-mtile halves to halve accumulator pressure (16 regs live, not 32).
  {
    const bool isv = wave >= 6;
    const int hw = isv ? wave - 6 : wave;          // head written
    const int ntg0 = (isv ? 24 : 12) + 2 * hw;     // global packed ntile
    const float bv0 = qkv_b[(ntg0 + 0) * 16 + l15];
    const float bv1 = qkv_b[(ntg0 + 1) * 16 + l15];
#pragma unroll
    for (int half = 0; half < 2; ++half) {
      f32x4 acc[2][2];
      acc[0][0] = (f32x4){bv0, bv0, bv0, bv0};
      acc[1][0] = (f32x4){bv0, bv0, bv0, bv0};
      acc[0][1] = (f32x4){bv1, bv1, bv1, bv1};
      acc[1][1] = (f32x4){bv1, bv1, bv1, bv1};
#pragma unroll
      for (int ks = 0; ks < 6; ++ks) {
        bf16x8 bf[2];
#pragma unroll
        for (int n = 0; n < 2; ++n)
          bf[n] = *reinterpret_cast<const bf16x8*>(wqkv + ((size_t)((ntg0 + n) * 6 + ks) * 64 + lane) * 8);
#pragma unroll
        for (int m = 0; m < 2; ++m) {
          uint32_t row = (uint32_t)((half * 2 + m) * 16 + l15);
          bf16x8 a = *reinterpret_cast<const bf16x8*>(smem + XOFF + row * 384u + swzA(row, (uint32_t)(ks * 64 + g16)));
#pragma unroll
          for (int n = 0; n < 2; ++n)
            acc[m][n] = __builtin_amdgcn_mfma_f32_16x16x32_bf16(a, bf[n], acc[m][n], 0, 0, 0);
        }
      }
      if (isv) {
        // vT: [d][tok] -> 4 consecutive tokens pack into one 8B store
#pragma unroll
        for (int n = 0; n < 2; ++n) {
          int d = (n << 4) + l15;
          uint32_t rowbase = VOFF + (uint32_t)hw * 4096u + (uint32_t)d * 128u;
#pragma unroll
          for (int m = 0; m < 2; ++m) {
            uint32_t c0 = (uint32_t)(((half * 2 + m) * 16 + rloc0) * 2);
            bf16x4v hv = (bf16x4v){(__bf16)acc[m][n][0], (__bf16)acc[m][n][1],
                                   (__bf16)acc[m][n][2], (__bf16)acc[m][n][3]};
            *reinterpret_cast<bf16x4v*>(smem + rowbase + swzA((uint32_t)d, c0)) = hv;
          }
        }
      } else {
#pragma unroll
        for (int n = 0; n < 2; ++n) {
          int d = (n << 4) + l15;
#pragma unroll
          for (int m = 0; m < 2; ++m)
#pragma unroll
            for (int r = 0; r < 4; ++r) {
              uint32_t row = (uint32_t)((half * 2 + m) * 16 + rloc0 + r);
              uint32_t addr = KOFF + (uint32_t)hw * 4096u + row * 64u + swzQ(row, (uint32_t)(d * 2));
              *reinterpret_cast<__bf16*>(smem + addr) = (__bf16)acc[m][n][r];
            }
        }
      }
    }
  }

  // ---- Phase 2b: own q block (rows 32*(wave&1)+0..31, cols 32h..32h+31) -> regs ----
  f32x4 qacc[2][2];
  {
#pragma unroll
    for (int n = 0; n < 2; ++n) {
      float bv = qkv_b[(2 * h + n) * 16 + l15] * QKSCALE;
      qacc[0][n] = (f32x4){bv, bv, bv, bv};
      qacc[1][n] = (f32x4){bv, bv, bv, bv};
    }
#pragma unroll
    for (int ks = 0; ks < 6; ++ks) {
      bf16x8 bf[2];
#pragma unroll
      for (int n = 0; n < 2; ++n)
        bf[n] = *reinterpret_cast<const bf16x8*>(wqkv + ((size_t)((2 * h + n) * 6 + ks) * 64 + lane) * 8);
#pragma unroll
      for (int m = 0; m < 2; ++m) {
        uint32_t row = (uint32_t)((mbase + m) * 16 + l15);
        bf16x8 a = *reinterpret_cast<const bf16x8*>(smem + XOFF + row * 384u + swzA(row, (uint32_t)(ks * 64 + g16)));
#pragma unroll
        for (int n = 0; n < 2; ++n)
          qacc[m][n] = __builtin_amdgcn_mfma_f32_16x16x32_bf16(a, bf[n], qacc[m][n], 0, 0, 0);
      }
    }
  }
  __syncthreads();   // x reads + k/v writes retire; x region becomes per-wave scratch

  const uint32_t sb = XOFF + (uint32_t)wave * 2048u;   // wave-private scratch
  const uint32_t vbase = VOFF + (uint32_t)h * 4096u;
  const uint32_t kbase = KOFF + (uint32_t)h * 4096u;

  // ---- q C->A transpose via private scratch ([32][32] bf16 stride 64B swzQ) ----
  bf16x8 qa0, qa1;
  {
#pragma unroll
    for (int m = 0; m < 2; ++m)
#pragma unroll
      for (int n = 0; n < 2; ++n)
#pragma unroll
        for (int r = 0; r < 4; ++r) {
          uint32_t lr = (uint32_t)(m * 16 + rloc0 + r);
          uint32_t lc = (uint32_t)((n << 4) + l15);
          *reinterpret_cast<__bf16*>(smem + sb + lr * 64u + swzQ(lr, lc * 2u)) = (__bf16)qacc[m][n][r];
        }
    asm volatile("s_waitcnt lgkmcnt(0)" ::: "memory");
    qa0 = *reinterpret_cast<const bf16x8*>(smem + sb + (uint32_t)l15 * 64u + swzQ((uint32_t)l15, (uint32_t)g16));
    uint32_t r1 = (uint32_t)(l15 + 16);
    qa1 = *reinterpret_cast<const bf16x8*>(smem + sb + r1 * 64u + swzQ(r1, (uint32_t)g16));
  }

  f32x4 o0a, o0b;  // normalized t0 output, held across the barrier

  // ---- t0: QK^T -> exp -> P0 (own scratch, no barrier) -> PV -> normalize ----
  {
    f32x4 s[4];
    const float* bt = bias_c + (size_t)((h * 4 + mbase) * 4 * 64 + lane) * 4;
#pragma unroll
    for (int nt = 0; nt < 4; ++nt)
      s[nt] = *reinterpret_cast<const f32x4*>(bt + (size_t)nt * 256);
#pragma unroll
    for (int nt = 0; nt < 4; ++nt) {
      uint32_t krow = (uint32_t)(nt * 16 + l15);
      bf16x8 kb = *reinterpret_cast<const bf16x8*>(smem + kbase + krow * 64u + swzQ(krow, (uint32_t)g16));
      s[nt] = __builtin_amdgcn_mfma_f32_16x16x32_bf16(qa0, kb, s[nt], 0, 0, 0);
    }
    // P0 = exp(S0) into own scratch ([16][64] swzA); scratch reads (qa) already retired
#pragma unroll
    for (int r = 0; r < 4; ++r) {
      int rl = rloc0 + r;
#pragma unroll
      for (int nt = 0; nt < 4; ++nt) {
        float e = __expf(s[nt][r]);
        uint32_t addr = sb + (uint32_t)rl * 128u + swzA((uint32_t)rl, (uint32_t)((nt * 16 + l15) * 2));
        *reinterpret_cast<__bf16*>(smem + addr) = (__bf16)e;
      }
    }
    asm volatile("s_waitcnt lgkmcnt(0)" ::: "memory");
    f32x4 o[3];
    o[0] = (f32x4){0.f, 0.f, 0.f, 0.f};
    o[1] = (f32x4){0.f, 0.f, 0.f, 0.f};
    o[2] = (f32x4){0.f, 0.f, 0.f, 0.f};
#pragma unroll
    for (int ks = 0; ks < 2; ++ks) {
      bf16x8 pa = *reinterpret_cast<const bf16x8*>(smem + sb + (uint32_t)l15 * 128u + swzA((uint32_t)l15, (uint32_t)(ks * 64 + g16)));
#pragma unroll
      for (int n2 = 0; n2 < 2; ++n2) {
        uint32_t vrow = (uint32_t)(n2 * 16 + l15);
        bf16x8 vb = *reinterpret_cast<const bf16x8*>(smem + vbase + vrow * 128u + swzA(vrow, (uint32_t)(ks * 64 + g16)));
        o[n2] = __builtin_amdgcn_mfma_f32_16x16x32_bf16(pa, vb, o[n2], 0, 0, 0);
      }
      bf16x8 ob = *reinterpret_cast<const bf16x8*>(smem + ONESOFF + (uint32_t)l15 * 128u + swzA((uint32_t)l15, (uint32_t)(ks * 64 + g16)));
      o[2] = __builtin_amdgcn_mfma_f32_16x16x32_bf16(pa, ob, o[2], 0, 0, 0);
    }
#pragma unroll
    for (int r = 0; r < 4; ++r) {
      float is = __builtin_amdgcn_rcpf(__shfl(o[2][r], lane & 48));
      o[0][r] *= is;
      o[1][r] *= is;
    }
    o0a = o[0];
    o0b = o[1];
  }

  // ---- t1 QK^T (k region still intact; all k reads complete before the barrier) ----
  f32x4 s1[4];
  {
    const float* bt = bias_c + (size_t)((h * 4 + mbase + 1) * 4 * 64 + lane) * 4;
#pragma unroll
    for (int nt = 0; nt < 4; ++nt)
      s1[nt] = *reinterpret_cast<const f32x4*>(bt + (size_t)nt * 256);
#pragma unroll
    for (int nt = 0; nt < 4; ++nt) {
      uint32_t krow = (uint32_t)(nt * 16 + l15);
      bf16x8 kb = *reinterpret_cast<const bf16x8*>(smem + kbase + krow * 64u + swzQ(krow, (uint32_t)g16));
      s1[nt] = __builtin_amdgcn_mfma_f32_16x16x32_bf16(qa1, kb, s1[nt], 0, 0, 0);
    }
  }
  __syncthreads();   // all k + scratch reads retire; k region -> P1, x region -> attn_o

  // ---- t1: exp -> P1 (k region wave slot) -> PV -> normalize ----
  f32x4 o1a, o1b;
  {
    const uint32_t pb1 = KOFF + (uint32_t)wave * 2048u;
#pragma unroll
    for (int r = 0; r < 4; ++r) {
      int rl = rloc0 + r;
#pragma unroll
      for (int nt = 0; nt < 4; ++nt) {
        float e = __expf(s1[nt][r]);
        uint32_t addr = pb1 + (uint32_t)rl * 128u + swzA((uint32_t)rl, (uint32_t)((nt * 16 + l15) * 2));
        *reinterpret_cast<__bf16*>(smem + addr) = (__bf16)e;
      }
    }
    asm volatile("s_waitcnt lgkmcnt(0)" ::: "memory");
    f32x4 o[3];
    o[0] = (f32x4){0.f, 0.f, 0.f, 0.f};
    o[1] = (f32x4){0.f, 0.f, 0.f, 0.f};
    o[2] = (f32x4){0.f, 0.f, 0.f, 0.f};
#pragma unroll
    for (int ks = 0; ks < 2; ++ks) {
      bf16x8 pa = *reinterpret_cast<const bf16x8*>(smem + pb1 + (uint32_t)l15 * 128u + swzA((uint32_t)l15, (uint32_t)(ks * 64 + g16)));
#pragma unroll
      for (int n2 = 0; n2 < 2; ++n2) {
        uint32_t vrow = (uint32_t)(n2 * 16 + l15);
        bf16x8 vb = *reinterpret_cast<const bf16x8*>(smem + vbase + vrow * 128u + swzA(vrow, (uint32_t)(ks * 64 + g16)));
        o[n2] = __builtin_amdgcn_mfma_f32_16x16x32_bf16(pa, vb, o[n2], 0, 0, 0);
      }
      bf16x8 ob = *reinterpret_cast<const bf16x8*>(smem + ONESOFF + (uint32_t)l15 * 128u + swzA((uint32_t)l15, (uint32_t)(ks * 64 + g16)));
      o[2] = __builtin_amdgcn_mfma_f32_16x16x32_bf16(pa, ob, o[2], 0, 0, 0);
    }
#pragma unroll
    for (int r = 0; r < 4; ++r) {
      float is = __builtin_amdgcn_rcpf(__shfl(o[2][r], lane & 48));
      o[0][r] *= is;
      o[1][r] *= is;
    }
    o1a = o[0];
    o1b = o[1];
  }

  // ---- attn_o writes for both tiles (x region, all scratch reads were pre-barrier) ----
  {
#pragma unroll
    for (int r = 0; r < 4; ++r) {
      int row0 = mbase * 16 + rloc0 + r;
      int row1 = row0 + 16;
#pragma unroll
      for (int n2 = 0; n2 < 2; ++n2) {
        int col = h * 32 + n2 * 16 + l15;
        float v0 = (n2 == 0) ? o0a[r] : o0b[r];
        float v1 = (n2 == 0) ? o1a[r] : o1b[r];
        uint32_t a0 = XOFF + (uint32_t)row0 * 384u + swzA((uint32_t)row0, (uint32_t)(col * 2));
        uint32_t a1 = XOFF + (uint32_t)row1 * 384u + swzA((uint32_t)row1, (uint32_t)(col * 2));
        *reinterpret_cast<__bf16*>(smem + a0) = (__bf16)v0;
        *reinterpret_cast<__bf16*>(smem + a1) = (__bf16)v1;
      }
    }
  }
  __syncthreads();

  // ---- Phase 4: proj. wave owns ntile=wave (cols 16w..16w+15), all 4 mtiles ----
  {
    const int ntp = wave;
    const float pb = proj_b[ntp * 16 + l15];
    f32x4 po[4];
#pragma unroll
    for (int m = 0; m < 4; ++m) po[m] = (f32x4){pb, pb, pb, pb};
#pragma unroll
    for (int ks = 0; ks < 6; ++ks) {
      bf16x8 bfp = *reinterpret_cast<const bf16x8*>(wproj + ((size_t)(ntp * 6 + ks) * 64 + lane) * 8);
#pragma unroll
      for (int m = 0; m < 4; ++m) {
        uint32_t row = (uint32_t)(m * 16 + l15);
        bf16x8 a = *reinterpret_cast<const bf16x8*>(smem + XOFF + row * 384u + swzA(row, (uint32_t)(ks * 64 + g16)));
        po[m] = __builtin_amdgcn_mfma_f32_16x16x32_bf16(a, bfp, po[m], 0, 0, 0);
      }
    }
    float* outg = out + (size_t)b * (TOK * CDIM);
    const int col = ntp * 16 + l15;
#pragma unroll
    for (int m = 0; m < 4; ++m)
#pragma unroll
      for (int r = 0; r < 4; ++r) {
        int row = m * 16 + rloc0 + r;
        if (row < TOK) outg[row * CDIM + col] = po[m][r];
      }
  }
}

extern "C" void kernel_launch(void* const* d_in, const int* in_sizes, int n_in,
                              void* d_out, int out_size, void* d_ws, size_t ws_size,
                              hipStream_t stream) {
  const float* x = (const float*)d_in[0];
  // d_in[1] = q_global : unused by the reference
  const float* qkv_w = (const float*)d_in[2];
  const float* qkv_b = (const float*)d_in[3];
  const float* proj_w = (const float*)d_in[4];
  const float* proj_b = (const float*)d_in[5];
  const float* rpb = (const float*)d_in[6];

  unsigned short* wqkv = (unsigned short*)d_ws;                 // 36*6*64*8 bf16 = 221184 B
  unsigned short* wproj = wqkv + (size_t)36 * 6 * 64 * 8;       // 12*6*64*8 bf16 = 73728 B
  float* bias_c = (float*)(wproj + (size_t)12 * 6 * 64 * 8);    // 6*4*4*64*4 f32 = 98304 B

  wa_pack_w<<<(36 * 6 * 64 + 255) / 256, 256, 0, stream>>>(qkv_w, wqkv, 36, 576, 12, QKSCALE);
  wa_pack_w<<<(12 * 6 * 64 + 255) / 256, 256, 0, stream>>>(proj_w, wproj, 12, 192, 0, 1.0f);
  wa_pack_bias<<<(NHEAD * 4 * 4 * 64 + 255) / 256, 256, 0, stream>>>(rpb, bias_c);

  hipFuncSetAttribute((const void*)wa_main, hipFuncAttributeMaxDynamicSharedMemorySize, (int)SMEM_BYTES);
  wa_main<<<2048, THREADS, SMEM_BYTES, stream>>>(x, qkv_b, proj_b, bias_c, wqkv, wproj, (float*)d_out);
}

// Round 6
// 97.572 us; speedup vs baseline: 1.4632x; 1.4632x over previous
//
#include <hip/hip_runtime.h>
#include <stdint.h>

typedef __bf16 bf16x8 __attribute__((ext_vector_type(8)));
typedef __bf16 bf16x4v __attribute__((ext_vector_type(4)));
typedef float f32x4 __attribute__((ext_vector_type(4)));

#define TOK 49
#define CDIM 192
#define NHEAD 6
#define THREADS 512
#define QKSCALE 0.17677669529663687f

// LDS (75776 B total -> 2 blocks/CU at 512 threads = 4 waves/SIMD -> 128 VGPR budget):
// X region @0      (24576): ph1-2: x [64][192] bf16 stride 384B swzA
//                           ph3a: per-wave scratch 3KB (3 x [16][32] swzQ q transpose) @ XOFF+wave*3072
//                           ph3b + ph4: attn_o [64][192] swzA
// K region @24576  (24576): ph2-3a: k 6x[64][32] swzQ; ph3b: P per-wave [16][64] swzA @ KOFF+wave*2048
// V region @49152  (24576): vT 6x[32][64] stride 128B swzA
// ones    @73728  (2048):   [16][64] stride 128B, row0 = 1.0, rows 1-15 = 0 (shared sum column)
#define XOFF   0u
#define KOFF   24576u
#define VOFF   49152u
#define ONESOFF 73728u
#define SMEM_BYTES 75776u

__device__ __forceinline__ unsigned short f2bf(float f) {
  unsigned u = __float_as_uint(f);
  return (unsigned short)((u + 0x7fffu + ((u >> 16) & 1u)) >> 16);  // RNE (host-pack kernels only)
}
__device__ __forceinline__ void st_bf(char* p, float f) { *reinterpret_cast<__bf16*>(p) = (__bf16)f; }
// XOR-swizzle byte-in-row for stride%128==0 tiles (bits 4-6)
__device__ __forceinline__ uint32_t swzA(uint32_t row, uint32_t b) { return b ^ ((row & 7u) << 4); }
// XOR-swizzle for stride-64B tiles (bits 4-5)
__device__ __forceinline__ uint32_t swzQ(uint32_t row, uint32_t b) { return b ^ (((row >> 1) & 3u) << 4); }

// Pack fp32 weight matrix [192][NT*16] row-major into bf16 MFMA B-fragments:
// frag (nt, ks): lane l gets B[ks*32 + (l>>4)*8 + j][nt*16 + (l&15)], j=0..7, stored
// contiguously at ((nt*6+ks)*64 + l)*8 bf16. Columns nt < nscale are pre-multiplied by scale.
__global__ void wa_pack_w(const float* __restrict__ w, unsigned short* __restrict__ outp,
                          int NT, int ncols, int nscale, float scale) {
  int idx = blockIdx.x * blockDim.x + threadIdx.x;
  if (idx >= NT * 6 * 64) return;
  int l = idx & 63;
  int frag = idx >> 6;
  int ks = frag % 6;
  int nt = frag / 6;
  float sc = (nt < nscale) ? scale : 1.0f;
  int n = nt * 16 + (l & 15);
  int k0 = ks * 32 + ((l >> 4) << 3);
  unsigned short v[8];
#pragma unroll
  for (int j = 0; j < 8; ++j) v[j] = f2bf(w[(k0 + j) * ncols + n] * sc);
  ushort4* dst = reinterpret_cast<ushort4*>(outp + (size_t)idx * 8);
  dst[0] = make_ushort4(v[0], v[1], v[2], v[3]);
  dst[1] = make_ushort4(v[4], v[5], v[6], v[7]);
}

// Precompute relative-position bias in MFMA C-fragment layout:
// out[((head*4 + mtile)*4 + nt)*64 + lane][r] = bias(row=mtile*16+(lane>>4)*4+r, col=nt*16+(lane&15))
// with -1e30 for masked (row>=49 || col>=49) entries so softmax masking is free.
__global__ void wa_pack_bias(const float* __restrict__ rpb, float* __restrict__ outb) {
  int idx = blockIdx.x * blockDim.x + threadIdx.x;
  if (idx >= NHEAD * 4 * 4 * 64) return;
  int lane = idx & 63;
  int nt = (idx >> 6) & 3;
  int mtile = (idx >> 8) & 3;
  int head = idx >> 10;
  int col = nt * 16 + (lane & 15);
  int row0 = mtile * 16 + ((lane >> 4) << 2);
  float4 v;
  float* vp = reinterpret_cast<float*>(&v);
#pragma unroll
  for (int r = 0; r < 4; ++r) {
    int row = row0 + r;
    float val = -1e30f;
    if (row < TOK && col < TOK) {
      int ri = (row / 7 - col / 7 + 6) * 13 + (row % 7 - col % 7 + 6);
      val = rpb[ri * NHEAD + head];
    }
    vp[r] = val;
  }
  *reinterpret_cast<float4*>(outb + (size_t)idx * 4) = v;
}

__global__ __launch_bounds__(THREADS, 4) void wa_main(
    const float* __restrict__ x,
    const float* __restrict__ qkv_b,
    const float* __restrict__ proj_b,
    const float* __restrict__ bias_c,          // C-fragment-layout bias table
    const unsigned short* __restrict__ wqkv,   // packed 36 ntiles (q cols pre-scaled)
    const unsigned short* __restrict__ wproj,  // packed 12 ntiles
    float* __restrict__ out) {
  extern __shared__ __align__(16) char smem[];
  const int tid = threadIdx.x;
  const int lane = tid & 63;
  const int wave = __builtin_amdgcn_readfirstlane(tid >> 6);  // wave-uniform -> SGPR (0..7)
  const int l15 = lane & 15;
  const int g16 = (lane >> 4) << 4;   // byte offset of this lane-group's 16B k-slice
  const int rloc0 = (lane >> 4) << 2;
  const int b = blockIdx.x;
  const float* xg = x + (size_t)b * (TOK * CDIM);
  const int mt = wave & 3;            // attention m-tile owned by this wave
  const int hgrp = wave >> 2;         // head parity group: heads {hgrp, hgrp+2, hgrp+4}

  // ---- Phase 1: x -> LDS bf16 [64][192] (rows 49..63 zero); ones tile fill ----
  for (int c = tid; c < 64 * 48; c += THREADS) {
    int r = c / 48;
    int cc = (c % 48) * 4;
    uint32_t addr = XOFF + (uint32_t)r * 384u + swzA((uint32_t)r, (uint32_t)(cc * 2));
    bf16x4v hv;
    if (r < TOK) {
      const float4 v = *reinterpret_cast<const float4*>(xg + r * CDIM + cc);
      hv = (bf16x4v){(__bf16)v.x, (__bf16)v.y, (__bf16)v.z, (__bf16)v.w};
    } else {
      hv = (bf16x4v){(__bf16)0.f, (__bf16)0.f, (__bf16)0.f, (__bf16)0.f};
    }
    *reinterpret_cast<bf16x4v*>(smem + addr) = hv;
  }
  if (tid < 128) {
    // ones tile: 2048B = 128 x 16B. Row 0 (first 8 stores) = bf16(1.0), rest 0.
    uint4 fill = (tid < 8) ? make_uint4(0x3F803F80u, 0x3F803F80u, 0x3F803F80u, 0x3F803F80u)
                           : make_uint4(0u, 0u, 0u, 0u);
    *reinterpret_cast<uint4*>(smem + ONESOFF + (uint32_t)tid * 16u) = fill;
  }
  __syncthreads();

  // ---- Phase 2a: k (waves 0-3) or v (waves 4-7), 3 ntiles x 4 mtiles each -> LDS ----
  {
    const bool isv = wave >= 4;
    const int ntg0 = 12 + (isv ? 12 : 0) + 3 * (wave & 3);
#pragma unroll
    for (int i = 0; i < 3; ++i) {
      const int nt = ntg0 + i;
      const float bv = qkv_b[nt * 16 + l15];
      f32x4 acc[4];
#pragma unroll
      for (int m = 0; m < 4; ++m) acc[m] = (f32x4){bv, bv, bv, bv};
#pragma unroll
      for (int ks = 0; ks < 6; ++ks) {
        bf16x8 bf = *reinterpret_cast<const bf16x8*>(wqkv + ((size_t)(nt * 6 + ks) * 64 + lane) * 8);
#pragma unroll
        for (int m = 0; m < 4; ++m) {
          uint32_t row = (uint32_t)(m * 16 + l15);
          bf16x8 a = *reinterpret_cast<const bf16x8*>(smem + XOFF + row * 384u + swzA(row, (uint32_t)(ks * 64 + g16)));
          acc[m] = __builtin_amdgcn_mfma_f32_16x16x32_bf16(a, bf, acc[m], 0, 0, 0);
        }
      }
      const int rem = isv ? (nt - 24) : (nt - 12);
      const int hw = rem >> 1;
      const int d = ((rem & 1) << 4) + l15;
      if (isv) {
        uint32_t rowbase = VOFF + (uint32_t)hw * 4096u + (uint32_t)d * 128u;
#pragma unroll
        for (int m = 0; m < 4; ++m) {
          uint32_t c0 = (uint32_t)((m * 16 + rloc0) * 2);
          bf16x4v hv = (bf16x4v){(__bf16)acc[m][0], (__bf16)acc[m][1],
                                 (__bf16)acc[m][2], (__bf16)acc[m][3]};
          *reinterpret_cast<bf16x4v*>(smem + rowbase + swzA((uint32_t)d, c0)) = hv;
        }
      } else {
#pragma unroll
        for (int m = 0; m < 4; ++m)
#pragma unroll
          for (int r = 0; r < 4; ++r) {
            uint32_t row = (uint32_t)(m * 16 + rloc0 + r);
            uint32_t addr = KOFF + (uint32_t)hw * 4096u + row * 64u + swzQ(row, (uint32_t)(d * 2));
            st_bf(smem + addr, acc[m][r]);
          }
      }
    }
  }

  // ---- Phase 2b: q for this wave's 3 attention units (rows mt*16..+15, cols 32h..) ----
  f32x4 qacc[3][2];
  {
#pragma unroll
    for (int j = 0; j < 3; ++j) {
      const int hj = hgrp + 2 * j;
#pragma unroll
      for (int n = 0; n < 2; ++n) {
        float bv = qkv_b[(2 * hj + n) * 16 + l15] * QKSCALE;
        qacc[j][n] = (f32x4){bv, bv, bv, bv};
      }
    }
#pragma unroll
    for (int ks = 0; ks < 6; ++ks) {
      uint32_t row = (uint32_t)(mt * 16 + l15);
      bf16x8 a = *reinterpret_cast<const bf16x8*>(smem + XOFF + row * 384u + swzA(row, (uint32_t)(ks * 64 + g16)));
#pragma unroll
      for (int j = 0; j < 3; ++j) {
        const int hj = hgrp + 2 * j;
#pragma unroll
        for (int n = 0; n < 2; ++n) {
          bf16x8 bf = *reinterpret_cast<const bf16x8*>(wqkv + ((size_t)((2 * hj + n) * 6 + ks) * 64 + lane) * 8);
          qacc[j][n] = __builtin_amdgcn_mfma_f32_16x16x32_bf16(a, bf, qacc[j][n], 0, 0, 0);
        }
      }
    }
  }
  __syncthreads();   // x reads + k/v writes retire; x region becomes per-wave scratch

  // ---- Phase 3a: q C->A transpose via private scratch (3 x [16][32] swzQ, 1KB each) ----
  bf16x8 qa[3];
  {
    const uint32_t sb = XOFF + (uint32_t)wave * 3072u;
#pragma unroll
    for (int j = 0; j < 3; ++j)
#pragma unroll
      for (int n = 0; n < 2; ++n)
#pragma unroll
        for (int r = 0; r < 4; ++r) {
          uint32_t lr = (uint32_t)(rloc0 + r);
          uint32_t lc = (uint32_t)((n << 4) + l15);
          st_bf(smem + sb + (uint32_t)j * 1024u + lr * 64u + swzQ(lr, lc * 2u), qacc[j][n][r]);
        }
    asm volatile("s_waitcnt lgkmcnt(0)" ::: "memory");
#pragma unroll
    for (int j = 0; j < 3; ++j)
      qa[j] = *reinterpret_cast<const bf16x8*>(smem + sb + (uint32_t)j * 1024u + (uint32_t)l15 * 64u + swzQ((uint32_t)l15, (uint32_t)g16));
  }

  // ---- Phase 3b: QK^T for all 3 units (bias preloaded into accumulators) ----
  f32x4 s[3][4];
#pragma unroll
  for (int j = 0; j < 3; ++j) {
    const int hj = hgrp + 2 * j;
    const float* bt = bias_c + (size_t)((hj * 4 + mt) * 4 * 64 + lane) * 4;
#pragma unroll
    for (int nt = 0; nt < 4; ++nt)
      s[j][nt] = *reinterpret_cast<const f32x4*>(bt + (size_t)nt * 256);
  }
#pragma unroll
  for (int j = 0; j < 3; ++j) {
    const int hj = hgrp + 2 * j;
    const uint32_t kbase = KOFF + (uint32_t)hj * 4096u;
#pragma unroll
    for (int nt = 0; nt < 4; ++nt) {
      uint32_t krow = (uint32_t)(nt * 16 + l15);
      bf16x8 kb = *reinterpret_cast<const bf16x8*>(smem + kbase + krow * 64u + swzQ(krow, (uint32_t)g16));
      s[j][nt] = __builtin_amdgcn_mfma_f32_16x16x32_bf16(qa[j], kb, s[j][nt], 0, 0, 0);
    }
  }
  __syncthreads();   // all k + scratch reads retire; k region -> P slots, x region -> attn_o

  // ---- Phase 3c: per unit: exp -> P (own slot) -> PV -> normalize -> attn_o ----
  {
    const uint32_t pbase = KOFF + (uint32_t)wave * 2048u;   // P [16][64] stride 128B swzA
#pragma unroll
    for (int j = 0; j < 3; ++j) {
      const int hj = hgrp + 2 * j;
      const uint32_t vbase = VOFF + (uint32_t)hj * 4096u;
      // ensure previous unit's P reads retired before overwriting the slot
      asm volatile("s_waitcnt lgkmcnt(0)" ::: "memory");
#pragma unroll
      for (int r = 0; r < 4; ++r) {
        int rl = rloc0 + r;
#pragma unroll
        for (int nt = 0; nt < 4; ++nt) {
          float e = __expf(s[j][nt][r]);
          uint32_t addr = pbase + (uint32_t)rl * 128u + swzA((uint32_t)rl, (uint32_t)((nt * 16 + l15) * 2));
          st_bf(smem + addr, e);
        }
      }
      asm volatile("s_waitcnt lgkmcnt(0)" ::: "memory");
      f32x4 o[3];
      o[0] = (f32x4){0.f, 0.f, 0.f, 0.f};
      o[1] = (f32x4){0.f, 0.f, 0.f, 0.f};
      o[2] = (f32x4){0.f, 0.f, 0.f, 0.f};
#pragma unroll
      for (int ks = 0; ks < 2; ++ks) {
        bf16x8 pa = *reinterpret_cast<const bf16x8*>(smem + pbase + (uint32_t)l15 * 128u + swzA((uint32_t)l15, (uint32_t)(ks * 64 + g16)));
#pragma unroll
        for (int n2 = 0; n2 < 2; ++n2) {
          uint32_t vrow = (uint32_t)(n2 * 16 + l15);
          bf16x8 vb = *reinterpret_cast<const bf16x8*>(smem + vbase + vrow * 128u + swzA(vrow, (uint32_t)(ks * 64 + g16)));
          o[n2] = __builtin_amdgcn_mfma_f32_16x16x32_bf16(pa, vb, o[n2], 0, 0, 0);
        }
        bf16x8 ob = *reinterpret_cast<const bf16x8*>(smem + ONESOFF + (uint32_t)l15 * 128u + swzA((uint32_t)l15, (uint32_t)(ks * 64 + g16)));
        o[2] = __builtin_amdgcn_mfma_f32_16x16x32_bf16(pa, ob, o[2], 0, 0, 0);
      }
#pragma unroll
      for (int r = 0; r < 4; ++r) {
        float is = __builtin_amdgcn_rcpf(__shfl(o[2][r], lane & 48));
        int row = mt * 16 + rloc0 + r;
#pragma unroll
        for (int n2 = 0; n2 < 2; ++n2) {
          int col = hj * 32 + n2 * 16 + l15;
          uint32_t addr = XOFF + (uint32_t)row * 384u + swzA((uint32_t)row, (uint32_t)(col * 2));
          st_bf(smem + addr, o[n2][r] * is);
        }
      }
    }
  }
  __syncthreads();

  // ---- Phase 4: proj. wave owns mtile = wave>>1, ntiles (wave&1)*6 .. +5 ----
  {
    const int m = wave >> 1;
    const int ntb = (wave & 1) * 6;
    bf16x8 a[6];
#pragma unroll
    for (int ks = 0; ks < 6; ++ks) {
      uint32_t row = (uint32_t)(m * 16 + l15);
      a[ks] = *reinterpret_cast<const bf16x8*>(smem + XOFF + row * 384u + swzA(row, (uint32_t)(ks * 64 + g16)));
    }
    float* outg = out + (size_t)b * (TOK * CDIM);
#pragma unroll
    for (int i = 0; i < 6; ++i) {
      const int nt = ntb + i;
      const float pb = proj_b[nt * 16 + l15];
      f32x4 po = (f32x4){pb, pb, pb, pb};
#pragma unroll
      for (int ks = 0; ks < 6; ++ks) {
        bf16x8 bfp = *reinterpret_cast<const bf16x8*>(wproj + ((size_t)(nt * 6 + ks) * 64 + lane) * 8);
        po = __builtin_amdgcn_mfma_f32_16x16x32_bf16(a[ks], bfp, po, 0, 0, 0);
      }
      const int col = nt * 16 + l15;
#pragma unroll
      for (int r = 0; r < 4; ++r) {
        int row = m * 16 + rloc0 + r;
        if (row < TOK) outg[row * CDIM + col] = po[r];
      }
    }
  }
}

extern "C" void kernel_launch(void* const* d_in, const int* in_sizes, int n_in,
                              void* d_out, int out_size, void* d_ws, size_t ws_size,
                              hipStream_t stream) {
  const float* x = (const float*)d_in[0];
  // d_in[1] = q_global : unused by the reference
  const float* qkv_w = (const float*)d_in[2];
  const float* qkv_b = (const float*)d_in[3];
  const float* proj_w = (const float*)d_in[4];
  const float* proj_b = (const float*)d_in[5];
  const float* rpb = (const float*)d_in[6];

  unsigned short* wqkv = (unsigned short*)d_ws;                 // 36*6*64*8 bf16 = 221184 B
  unsigned short* wproj = wqkv + (size_t)36 * 6 * 64 * 8;       // 12*6*64*8 bf16 = 73728 B
  float* bias_c = (float*)(wproj + (size_t)12 * 6 * 64 * 8);    // 6*4*4*64*4 f32 = 98304 B

  wa_pack_w<<<(36 * 6 * 64 + 255) / 256, 256, 0, stream>>>(qkv_w, wqkv, 36, 576, 12, QKSCALE);
  wa_pack_w<<<(12 * 6 * 64 + 255) / 256, 256, 0, stream>>>(proj_w, wproj, 12, 192, 0, 1.0f);
  wa_pack_bias<<<(NHEAD * 4 * 4 * 64 + 255) / 256, 256, 0, stream>>>(rpb, bias_c);

  hipFuncSetAttribute((const void*)wa_main, hipFuncAttributeMaxDynamicSharedMemorySize, (int)SMEM_BYTES);
  wa_main<<<2048, THREADS, SMEM_BYTES, stream>>>(x, qkv_b, proj_b, bias_c, wqkv, wproj, (float*)d_out);
}

// Round 7
// 81.655 us; speedup vs baseline: 1.7484x; 1.1949x over previous
//
#include <hip/hip_runtime.h>
#include <stdint.h>

typedef __bf16 bf16x8 __attribute__((ext_vector_type(8)));
typedef __bf16 bf16x4v __attribute__((ext_vector_type(4)));
typedef float f32x4 __attribute__((ext_vector_type(4)));

#define TOK 49
#define CDIM 192
#define NHEAD 6
#define THREADS 768
#define QKSCALE 0.17677669529663687f

// LDS (75776 B total -> 2 blocks/CU at 768 threads; 24 waves/CU needs <=85 VGPR -> lean phases):
// X region @0      (24576): ph1-2: x [64][192] bf16 stride 384B swzA
//                           ph3: per-wave scratch [32][32]swzQ (q transpose), then P0 [16][64]swzA
//                           late ph3 + ph4: attn_o [64][192] swzA
// K region @24576  (24576): ph2-3a: k 6x[64][32] swzQ; ph3b: P1 per-wave [16][64] swzA @ KOFF+wave*2048
// V region @49152  (24576): vT 6x[32][64] stride 128B swzA
// ones    @73728  (2048):   [16][64] stride 128B, row0 = 1.0, rows 1-15 = 0 (shared sum column)
#define XOFF   0u
#define KOFF   24576u
#define VOFF   49152u
#define ONESOFF 73728u
#define SMEM_BYTES 75776u

__device__ __forceinline__ unsigned short f2bf(float f) {
  unsigned u = __float_as_uint(f);
  return (unsigned short)((u + 0x7fffu + ((u >> 16) & 1u)) >> 16);  // RNE (host-pack kernels only)
}
__device__ __forceinline__ void st_bf(char* p, float f) { *reinterpret_cast<__bf16*>(p) = (__bf16)f; }
// XOR-swizzle byte-in-row for stride%128==0 tiles (bits 4-6)
__device__ __forceinline__ uint32_t swzA(uint32_t row, uint32_t b) { return b ^ ((row & 7u) << 4); }
// XOR-swizzle for stride-64B tiles (bits 4-5)
__device__ __forceinline__ uint32_t swzQ(uint32_t row, uint32_t b) { return b ^ (((row >> 1) & 3u) << 4); }

// Pack fp32 weight matrix [192][NT*16] row-major into bf16 MFMA B-fragments:
// frag (nt, ks): lane l gets B[ks*32 + (l>>4)*8 + j][nt*16 + (l&15)], j=0..7, stored
// contiguously at ((nt*6+ks)*64 + l)*8 bf16. Columns nt < nscale are pre-multiplied by scale.
__global__ void wa_pack_w(const float* __restrict__ w, unsigned short* __restrict__ outp,
                          int NT, int ncols, int nscale, float scale) {
  int idx = blockIdx.x * blockDim.x + threadIdx.x;
  if (idx >= NT * 6 * 64) return;
  int l = idx & 63;
  int frag = idx >> 6;
  int ks = frag % 6;
  int nt = frag / 6;
  float sc = (nt < nscale) ? scale : 1.0f;
  int n = nt * 16 + (l & 15);
  int k0 = ks * 32 + ((l >> 4) << 3);
  unsigned short v[8];
#pragma unroll
  for (int j = 0; j < 8; ++j) v[j] = f2bf(w[(k0 + j) * ncols + n] * sc);
  ushort4* dst = reinterpret_cast<ushort4*>(outp + (size_t)idx * 8);
  dst[0] = make_ushort4(v[0], v[1], v[2], v[3]);
  dst[1] = make_ushort4(v[4], v[5], v[6], v[7]);
}

// Precompute relative-position bias in MFMA C-fragment layout:
// out[((head*4 + mtile)*4 + nt)*64 + lane][r] = bias(row=mtile*16+(lane>>4)*4+r, col=nt*16+(lane&15))
// with -1e30 for masked (row>=49 || col>=49) entries so softmax masking is free.
__global__ void wa_pack_bias(const float* __restrict__ rpb, float* __restrict__ outb) {
  int idx = blockIdx.x * blockDim.x + threadIdx.x;
  if (idx >= NHEAD * 4 * 4 * 64) return;
  int lane = idx & 63;
  int nt = (idx >> 6) & 3;
  int mtile = (idx >> 8) & 3;
  int head = idx >> 10;
  int col = nt * 16 + (lane & 15);
  int row0 = mtile * 16 + ((lane >> 4) << 2);
  float4 v;
  float* vp = reinterpret_cast<float*>(&v);
#pragma unroll
  for (int r = 0; r < 4; ++r) {
    int row = row0 + r;
    float val = -1e30f;
    if (row < TOK && col < TOK) {
      int ri = (row / 7 - col / 7 + 6) * 13 + (row % 7 - col % 7 + 6);
      val = rpb[ri * NHEAD + head];
    }
    vp[r] = val;
  }
  *reinterpret_cast<float4*>(outb + (size_t)idx * 4) = v;
}

__global__ __launch_bounds__(THREADS, 6) void wa_main(
    const float* __restrict__ x,
    const float* __restrict__ qkv_b,
    const float* __restrict__ proj_b,
    const float* __restrict__ bias_c,          // C-fragment-layout bias table
    const unsigned short* __restrict__ wqkv,   // packed 36 ntiles (q cols pre-scaled)
    const unsigned short* __restrict__ wproj,  // packed 12 ntiles
    float* __restrict__ out) {
  extern __shared__ __align__(16) char smem[];
  const int tid = threadIdx.x;
  const int lane = tid & 63;
  const int wave = __builtin_amdgcn_readfirstlane(tid >> 6);  // wave-uniform -> SGPR (0..11)
  const int l15 = lane & 15;
  const int g16 = (lane >> 4) << 4;   // byte offset of this lane-group's 16B k-slice
  const int rloc0 = (lane >> 4) << 2;
  const int b = blockIdx.x;
  const float* xg = x + (size_t)b * (TOK * CDIM);
  const int h = wave >> 1;            // head for q/attention phases
  const int mbase = (wave & 1) << 1;  // first of 2 owned q m-tiles

  // ---- Phase 1: x -> LDS bf16 [64][192] (rows 49..63 zero); ones tile fill ----
  for (int c = tid; c < 64 * 48; c += THREADS) {
    int r = c / 48;
    int cc = (c % 48) * 4;
    uint32_t addr = XOFF + (uint32_t)r * 384u + swzA((uint32_t)r, (uint32_t)(cc * 2));
    bf16x4v hv;
    if (r < TOK) {
      const float4 v = *reinterpret_cast<const float4*>(xg + r * CDIM + cc);
      hv = (bf16x4v){(__bf16)v.x, (__bf16)v.y, (__bf16)v.z, (__bf16)v.w};
    } else {
      hv = (bf16x4v){(__bf16)0.f, (__bf16)0.f, (__bf16)0.f, (__bf16)0.f};
    }
    *reinterpret_cast<bf16x4v*>(smem + addr) = hv;
  }
  if (tid < 128) {
    // ones tile: 2048B = 128 x 16B. Row 0 (first 8 stores) = bf16(1.0), rest 0.
    uint4 fill = (tid < 8) ? make_uint4(0x3F803F80u, 0x3F803F80u, 0x3F803F80u, 0x3F803F80u)
                           : make_uint4(0u, 0u, 0u, 0u);
    *reinterpret_cast<uint4*>(smem + ONESOFF + (uint32_t)tid * 16u) = fill;
  }
  __syncthreads();

  // ---- Phase 2a: k (waves 0-5) or v (waves 6-11): 2 ntiles x 4 mtiles -> LDS ----
  // Sequential per ntile (acc[4] = 16 regs live) to stay under the 85-VGPR cap.
  {
    const bool isv = wave >= 6;
    const int hw = isv ? wave - 6 : wave;          // head written
    const int ntg0 = (isv ? 24 : 12) + 2 * hw;     // global packed ntile
#pragma unroll
    for (int i = 0; i < 2; ++i) {
      const int nt = ntg0 + i;
      const float bv = qkv_b[nt * 16 + l15];
      f32x4 acc[4];
#pragma unroll
      for (int m = 0; m < 4; ++m) acc[m] = (f32x4){bv, bv, bv, bv};
#pragma unroll
      for (int ks = 0; ks < 6; ++ks) {
        bf16x8 bf = *reinterpret_cast<const bf16x8*>(wqkv + ((size_t)(nt * 6 + ks) * 64 + lane) * 8);
#pragma unroll
        for (int m = 0; m < 4; ++m) {
          uint32_t row = (uint32_t)(m * 16 + l15);
          bf16x8 a = *reinterpret_cast<const bf16x8*>(smem + XOFF + row * 384u + swzA(row, (uint32_t)(ks * 64 + g16)));
          acc[m] = __builtin_amdgcn_mfma_f32_16x16x32_bf16(a, bf, acc[m], 0, 0, 0);
        }
      }
      const int d = (i << 4) + l15;   // (nt - base) & 1 == i
      if (isv) {
        // vT: [d][tok] -> 4 consecutive tokens pack into one 8B store
        uint32_t rowbase = VOFF + (uint32_t)hw * 4096u + (uint32_t)d * 128u;
#pragma unroll
        for (int m = 0; m < 4; ++m) {
          uint32_t c0 = (uint32_t)((m * 16 + rloc0) * 2);
          bf16x4v hv = (bf16x4v){(__bf16)acc[m][0], (__bf16)acc[m][1],
                                 (__bf16)acc[m][2], (__bf16)acc[m][3]};
          *reinterpret_cast<bf16x4v*>(smem + rowbase + swzA((uint32_t)d, c0)) = hv;
        }
      } else {
#pragma unroll
        for (int m = 0; m < 4; ++m)
#pragma unroll
          for (int r = 0; r < 4; ++r) {
            uint32_t row = (uint32_t)(m * 16 + rloc0 + r);
            uint32_t addr = KOFF + (uint32_t)hw * 4096u + row * 64u + swzQ(row, (uint32_t)(d * 2));
            st_bf(smem + addr, acc[m][r]);
          }
      }
    }
  }

  // ---- Phase 2b: own q block (rows 32*(wave&1)+0..31, cols 32h..32h+31) -> regs ----
  f32x4 qacc[2][2];
  {
#pragma unroll
    for (int n = 0; n < 2; ++n) {
      float bv = qkv_b[(2 * h + n) * 16 + l15] * QKSCALE;
      qacc[0][n] = (f32x4){bv, bv, bv, bv};
      qacc[1][n] = (f32x4){bv, bv, bv, bv};
    }
#pragma unroll
    for (int ks = 0; ks < 6; ++ks) {
      bf16x8 bf[2];
#pragma unroll
      for (int n = 0; n < 2; ++n)
        bf[n] = *reinterpret_cast<const bf16x8*>(wqkv + ((size_t)((2 * h + n) * 6 + ks) * 64 + lane) * 8);
#pragma unroll
      for (int m = 0; m < 2; ++m) {
        uint32_t row = (uint32_t)((mbase + m) * 16 + l15);
        bf16x8 a = *reinterpret_cast<const bf16x8*>(smem + XOFF + row * 384u + swzA(row, (uint32_t)(ks * 64 + g16)));
#pragma unroll
        for (int n = 0; n < 2; ++n)
          qacc[m][n] = __builtin_amdgcn_mfma_f32_16x16x32_bf16(a, bf[n], qacc[m][n], 0, 0, 0);
      }
    }
  }
  __syncthreads();   // x reads + k/v writes retire; x region becomes per-wave scratch

  const uint32_t sb = XOFF + (uint32_t)wave * 2048u;   // wave-private scratch
  const uint32_t vbase = VOFF + (uint32_t)h * 4096u;
  const uint32_t kbase = KOFF + (uint32_t)h * 4096u;

  // ---- q C->A transpose via private scratch ([32][32] bf16 stride 64B swzQ) ----
  bf16x8 qa0, qa1;
  {
#pragma unroll
    for (int m = 0; m < 2; ++m)
#pragma unroll
      for (int n = 0; n < 2; ++n)
#pragma unroll
        for (int r = 0; r < 4; ++r) {
          uint32_t lr = (uint32_t)(m * 16 + rloc0 + r);
          uint32_t lc = (uint32_t)((n << 4) + l15);
          st_bf(smem + sb + lr * 64u + swzQ(lr, lc * 2u), qacc[m][n][r]);
        }
    asm volatile("s_waitcnt lgkmcnt(0)" ::: "memory");
    qa0 = *reinterpret_cast<const bf16x8*>(smem + sb + (uint32_t)l15 * 64u + swzQ((uint32_t)l15, (uint32_t)g16));
    uint32_t r1 = (uint32_t)(l15 + 16);
    qa1 = *reinterpret_cast<const bf16x8*>(smem + sb + r1 * 64u + swzQ(r1, (uint32_t)g16));
  }

  f32x4 o0a, o0b;  // normalized t0 output, held across the barrier

  // ---- t0: QK^T -> exp -> P0 (own scratch, no barrier) -> PV -> normalize ----
  {
    f32x4 s[4];
    const float* bt = bias_c + (size_t)((h * 4 + mbase) * 4 * 64 + lane) * 4;
#pragma unroll
    for (int nt = 0; nt < 4; ++nt)
      s[nt] = *reinterpret_cast<const f32x4*>(bt + (size_t)nt * 256);
#pragma unroll
    for (int nt = 0; nt < 4; ++nt) {
      uint32_t krow = (uint32_t)(nt * 16 + l15);
      bf16x8 kb = *reinterpret_cast<const bf16x8*>(smem + kbase + krow * 64u + swzQ(krow, (uint32_t)g16));
      s[nt] = __builtin_amdgcn_mfma_f32_16x16x32_bf16(qa0, kb, s[nt], 0, 0, 0);
    }
    // P0 = exp(S0) into own scratch ([16][64] swzA); DS ops are in-order per wave,
    // so these stores cannot bypass the qa reads above.
#pragma unroll
    for (int r = 0; r < 4; ++r) {
      int rl = rloc0 + r;
#pragma unroll
      for (int nt = 0; nt < 4; ++nt) {
        float e = __expf(s[nt][r]);
        uint32_t addr = sb + (uint32_t)rl * 128u + swzA((uint32_t)rl, (uint32_t)((nt * 16 + l15) * 2));
        st_bf(smem + addr, e);
      }
    }
    asm volatile("s_waitcnt lgkmcnt(0)" ::: "memory");
    f32x4 o[3];
    o[0] = (f32x4){0.f, 0.f, 0.f, 0.f};
    o[1] = (f32x4){0.f, 0.f, 0.f, 0.f};
    o[2] = (f32x4){0.f, 0.f, 0.f, 0.f};
#pragma unroll
    for (int ks = 0; ks < 2; ++ks) {
      bf16x8 pa = *reinterpret_cast<const bf16x8*>(smem + sb + (uint32_t)l15 * 128u + swzA((uint32_t)l15, (uint32_t)(ks * 64 + g16)));
#pragma unroll
      for (int n2 = 0; n2 < 2; ++n2) {
        uint32_t vrow = (uint32_t)(n2 * 16 + l15);
        bf16x8 vb = *reinterpret_cast<const bf16x8*>(smem + vbase + vrow * 128u + swzA(vrow, (uint32_t)(ks * 64 + g16)));
        o[n2] = __builtin_amdgcn_mfma_f32_16x16x32_bf16(pa, vb, o[n2], 0, 0, 0);
      }
      bf16x8 ob = *reinterpret_cast<const bf16x8*>(smem + ONESOFF + (uint32_t)l15 * 128u + swzA((uint32_t)l15, (uint32_t)(ks * 64 + g16)));
      o[2] = __builtin_amdgcn_mfma_f32_16x16x32_bf16(pa, ob, o[2], 0, 0, 0);
    }
#pragma unroll
    for (int r = 0; r < 4; ++r) {
      float is = __builtin_amdgcn_rcpf(__shfl(o[2][r], lane & 48));
      o[0][r] *= is;
      o[1][r] *= is;
    }
    o0a = o[0];
    o0b = o[1];
  }

  // ---- t1 QK^T (k region still intact; all k reads complete before the barrier) ----
  f32x4 s1[4];
  {
    const float* bt = bias_c + (size_t)((h * 4 + mbase + 1) * 4 * 64 + lane) * 4;
#pragma unroll
    for (int nt = 0; nt < 4; ++nt)
      s1[nt] = *reinterpret_cast<const f32x4*>(bt + (size_t)nt * 256);
#pragma unroll
    for (int nt = 0; nt < 4; ++nt) {
      uint32_t krow = (uint32_t)(nt * 16 + l15);
      bf16x8 kb = *reinterpret_cast<const bf16x8*>(smem + kbase + krow * 64u + swzQ(krow, (uint32_t)g16));
      s1[nt] = __builtin_amdgcn_mfma_f32_16x16x32_bf16(qa1, kb, s1[nt], 0, 0, 0);
    }
  }
  __syncthreads();   // all k + scratch reads retire; k region -> P1, x region -> attn_o

  // ---- t1: exp -> P1 (k region wave slot) -> PV -> normalize ----
  f32x4 o1a, o1b;
  {
    const uint32_t pb1 = KOFF + (uint32_t)wave * 2048u;
#pragma unroll
    for (int r = 0; r < 4; ++r) {
      int rl = rloc0 + r;
#pragma unroll
      for (int nt = 0; nt < 4; ++nt) {
        float e = __expf(s1[nt][r]);
        uint32_t addr = pb1 + (uint32_t)rl * 128u + swzA((uint32_t)rl, (uint32_t)((nt * 16 + l15) * 2));
        st_bf(smem + addr, e);
      }
    }
    asm volatile("s_waitcnt lgkmcnt(0)" ::: "memory");
    f32x4 o[3];
    o[0] = (f32x4){0.f, 0.f, 0.f, 0.f};
    o[1] = (f32x4){0.f, 0.f, 0.f, 0.f};
    o[2] = (f32x4){0.f, 0.f, 0.f, 0.f};
#pragma unroll
    for (int ks = 0; ks < 2; ++ks) {
      bf16x8 pa = *reinterpret_cast<const bf16x8*>(smem + pb1 + (uint32_t)l15 * 128u + swzA((uint32_t)l15, (uint32_t)(ks * 64 + g16)));
#pragma unroll
      for (int n2 = 0; n2 < 2; ++n2) {
        uint32_t vrow = (uint32_t)(n2 * 16 + l15);
        bf16x8 vb = *reinterpret_cast<const bf16x8*>(smem + vbase + vrow * 128u + swzA(vrow, (uint32_t)(ks * 64 + g16)));
        o[n2] = __builtin_amdgcn_mfma_f32_16x16x32_bf16(pa, vb, o[n2], 0, 0, 0);
      }
      bf16x8 ob = *reinterpret_cast<const bf16x8*>(smem + ONESOFF + (uint32_t)l15 * 128u + swzA((uint32_t)l15, (uint32_t)(ks * 64 + g16)));
      o[2] = __builtin_amdgcn_mfma_f32_16x16x32_bf16(pa, ob, o[2], 0, 0, 0);
    }
#pragma unroll
    for (int r = 0; r < 4; ++r) {
      float is = __builtin_amdgcn_rcpf(__shfl(o[2][r], lane & 48));
      o[0][r] *= is;
      o[1][r] *= is;
    }
    o1a = o[0];
    o1b = o[1];
  }

  // ---- attn_o writes for both tiles (x region, all scratch reads were pre-barrier) ----
  {
#pragma unroll
    for (int r = 0; r < 4; ++r) {
      int row0 = mbase * 16 + rloc0 + r;
      int row1 = row0 + 16;
#pragma unroll
      for (int n2 = 0; n2 < 2; ++n2) {
        int col = h * 32 + n2 * 16 + l15;
        float v0 = (n2 == 0) ? o0a[r] : o0b[r];
        float v1 = (n2 == 0) ? o1a[r] : o1b[r];
        uint32_t a0 = XOFF + (uint32_t)row0 * 384u + swzA((uint32_t)row0, (uint32_t)(col * 2));
        uint32_t a1 = XOFF + (uint32_t)row1 * 384u + swzA((uint32_t)row1, (uint32_t)(col * 2));
        st_bf(smem + a0, v0);
        st_bf(smem + a1, v1);
      }
    }
  }
  __syncthreads();

  // ---- Phase 4: proj. wave owns ntile=wave (cols 16w..16w+15), all 4 mtiles ----
  {
    const int ntp = wave;
    const float pb = proj_b[ntp * 16 + l15];
    f32x4 po[4];
#pragma unroll
    for (int m = 0; m < 4; ++m) po[m] = (f32x4){pb, pb, pb, pb};
#pragma unroll
    for (int ks = 0; ks < 6; ++ks) {
      bf16x8 bfp = *reinterpret_cast<const bf16x8*>(wproj + ((size_t)(ntp * 6 + ks) * 64 + lane) * 8);
#pragma unroll
      for (int m = 0; m < 4; ++m) {
        uint32_t row = (uint32_t)(m * 16 + l15);
        bf16x8 a = *reinterpret_cast<const bf16x8*>(smem + XOFF + row * 384u + swzA(row, (uint32_t)(ks * 64 + g16)));
        po[m] = __builtin_amdgcn_mfma_f32_16x16x32_bf16(a, bfp, po[m], 0, 0, 0);
      }
    }
    float* outg = out + (size_t)b * (TOK * CDIM);
    const int col = ntp * 16 + l15;
#pragma unroll
    for (int m = 0; m < 4; ++m)
#pragma unroll
      for (int r = 0; r < 4; ++r) {
        int row = m * 16 + rloc0 + r;
        if (row < TOK) outg[row * CDIM + col] = po[m][r];
      }
  }
}

extern "C" void kernel_launch(void* const* d_in, const int* in_sizes, int n_in,
                              void* d_out, int out_size, void* d_ws, size_t ws_size,
                              hipStream_t stream) {
  const float* x = (const float*)d_in[0];
  // d_in[1] = q_global : unused by the reference
  const float* qkv_w = (const float*)d_in[2];
  const float* qkv_b = (const float*)d_in[3];
  const float* proj_w = (const float*)d_in[4];
  const float* proj_b = (const float*)d_in[5];
  const float* rpb = (const float*)d_in[6];

  unsigned short* wqkv = (unsigned short*)d_ws;                 // 36*6*64*8 bf16 = 221184 B
  unsigned short* wproj = wqkv + (size_t)36 * 6 * 64 * 8;       // 12*6*64*8 bf16 = 73728 B
  float* bias_c = (float*)(wproj + (size_t)12 * 6 * 64 * 8);    // 6*4*4*64*4 f32 = 98304 B

  wa_pack_w<<<(36 * 6 * 64 + 255) / 256, 256, 0, stream>>>(qkv_w, wqkv, 36, 576, 12, QKSCALE);
  wa_pack_w<<<(12 * 6 * 64 + 255) / 256, 256, 0, stream>>>(proj_w, wproj, 12, 192, 0, 1.0f);
  wa_pack_bias<<<(NHEAD * 4 * 4 * 64 + 255) / 256, 256, 0, stream>>>(rpb, bias_c);

  hipFuncSetAttribute((const void*)wa_main, hipFuncAttributeMaxDynamicSharedMemorySize, (int)SMEM_BYTES);
  wa_main<<<2048, THREADS, SMEM_BYTES, stream>>>(x, qkv_b, proj_b, bias_c, wqkv, wproj, (float*)d_out);
}

// Round 8
// 77.955 us; speedup vs baseline: 1.8314x; 1.0475x over previous
//
#include <hip/hip_runtime.h>
#include <stdint.h>

typedef __bf16 bf16x8 __attribute__((ext_vector_type(8)));
typedef __bf16 bf16x4v __attribute__((ext_vector_type(4)));
typedef float f32x4 __attribute__((ext_vector_type(4)));

#define TOK 49
#define CDIM 192
#define NHEAD 6
#define THREADS 768
#define QKSCALE 0.17677669529663687f
#define LOG2E 1.4426950408889634f

// LDS (75776 B total -> 2 blocks/CU at 768 threads; 24 waves/CU needs <=85 VGPR -> lean phases):
// X region @0      (24576): ph1-2: x [64][192] bf16 stride 384B swzA
//                           ph3: per-wave scratch [32][32]swzQ (q^T), then P0 [16][64]swzA
//                           late ph3 + ph4: attn_o [64][192] swzA
// K region @24576  (24576): ph2-3a: k 6x[64][32] swzQ; ph3b: P1 per-wave [16][64] swzA @ KOFF+wave*2048
// V region @49152  (24576): vT 6x[32][64] stride 128B swzA
// ones    @73728  (2048):   [16][64] stride 128B, row0 = 1.0, rows 1-15 = 0 (shared sum row)
#define XOFF   0u
#define KOFF   24576u
#define VOFF   49152u
#define ONESOFF 73728u
#define SMEM_BYTES 75776u

__device__ __forceinline__ unsigned short f2bf(float f) {
  unsigned u = __float_as_uint(f);
  return (unsigned short)((u + 0x7fffu + ((u >> 16) & 1u)) >> 16);  // RNE (host-pack kernels only)
}
// XOR-swizzle byte-in-row for stride%128==0 tiles (bits 4-6)
__device__ __forceinline__ uint32_t swzA(uint32_t row, uint32_t b) { return b ^ ((row & 7u) << 4); }
// XOR-swizzle for stride-64B tiles (bits 4-5)
__device__ __forceinline__ uint32_t swzQ(uint32_t row, uint32_t b) { return b ^ (((row >> 1) & 3u) << 4); }

// Pack fp32 weight matrix [192][NT*16] row-major into bf16 MFMA B-fragments:
// frag (nt, ks): lane l gets B[ks*32 + (l>>4)*8 + j][nt*16 + (l&15)], j=0..7, stored
// contiguously at ((nt*6+ks)*64 + l)*8 bf16. Columns nt < nscale are pre-multiplied by scale.
// NOTE: on gfx950 A- and B-fragments share the same lane->element map, so this same
// packing serves as the A-fragment of W^T for the operand-swapped (transposed) GEMMs.
__global__ void wa_pack_w(const float* __restrict__ w, unsigned short* __restrict__ outp,
                          int NT, int ncols, int nscale, float scale) {
  int idx = blockIdx.x * blockDim.x + threadIdx.x;
  if (idx >= NT * 6 * 64) return;
  int l = idx & 63;
  int frag = idx >> 6;
  int ks = frag % 6;
  int nt = frag / 6;
  float sc = (nt < nscale) ? scale : 1.0f;
  int n = nt * 16 + (l & 15);
  int k0 = ks * 32 + ((l >> 4) << 3);
  unsigned short v[8];
#pragma unroll
  for (int j = 0; j < 8; ++j) v[j] = f2bf(w[(k0 + j) * ncols + n] * sc);
  ushort4* dst = reinterpret_cast<ushort4*>(outp + (size_t)idx * 8);
  dst[0] = make_ushort4(v[0], v[1], v[2], v[3]);
  dst[1] = make_ushort4(v[4], v[5], v[6], v[7]);
}

// Precompute relative-position bias in TRANSPOSED MFMA C-fragment layout (for S^T):
// out[((head*4 + qtile)*4 + ktile)*64 + lane][r] =
//   log2e * bias(qrow = qtile*16 + (lane&15), kcol = ktile*16 + (lane>>4)*4 + r)
// with -1e30 for masked (qrow>=49 || kcol>=49) entries so softmax masking is free.
__global__ void wa_pack_bias(const float* __restrict__ rpb, float* __restrict__ outb) {
  int idx = blockIdx.x * blockDim.x + threadIdx.x;
  if (idx >= NHEAD * 4 * 4 * 64) return;
  int lane = idx & 63;
  int kt = (idx >> 6) & 3;
  int qt = (idx >> 8) & 3;
  int head = idx >> 10;
  int qrow = qt * 16 + (lane & 15);
  int kcol0 = kt * 16 + ((lane >> 4) << 2);
  float4 v;
  float* vp = reinterpret_cast<float*>(&v);
#pragma unroll
  for (int r = 0; r < 4; ++r) {
    int kcol = kcol0 + r;
    float val = -1e30f;
    if (qrow < TOK && kcol < TOK) {
      int ri = (qrow / 7 - kcol / 7 + 6) * 13 + (qrow % 7 - kcol % 7 + 6);
      val = rpb[ri * NHEAD + head] * LOG2E;
    }
    vp[r] = val;
  }
  *reinterpret_cast<float4*>(outb + (size_t)idx * 4) = v;
}

__global__ __launch_bounds__(THREADS, 6) void wa_main(
    const float* __restrict__ x,
    const float* __restrict__ qkv_b,
    const float* __restrict__ proj_b,
    const float* __restrict__ bias_c,          // transposed C-fragment bias table (x log2e)
    const unsigned short* __restrict__ wqkv,   // packed 36 ntiles (q cols pre-scaled by QKSCALE*log2e)
    const unsigned short* __restrict__ wproj,  // packed 12 ntiles
    float* __restrict__ out) {
  extern __shared__ __align__(16) char smem[];
  const int tid = threadIdx.x;
  const int lane = tid & 63;
  const int wave = __builtin_amdgcn_readfirstlane(tid >> 6);  // wave-uniform -> SGPR (0..11)
  const int l15 = lane & 15;
  const int g16 = (lane >> 4) << 4;   // byte offset of this lane-group's 16B k-slice
  const int rloc0 = (lane >> 4) << 2;
  const int b = blockIdx.x;
  const float* xg = x + (size_t)b * (TOK * CDIM);
  const int h = wave >> 1;            // head for q/attention phases
  const int mbase = (wave & 1) << 1;  // first of 2 owned q m-tiles

  // ---- Phase 1: x -> LDS bf16 [64][192] (rows 49..63 zero); ones tile fill ----
  for (int c = tid; c < 64 * 48; c += THREADS) {
    int r = c / 48;
    int cc = (c % 48) * 4;
    uint32_t addr = XOFF + (uint32_t)r * 384u + swzA((uint32_t)r, (uint32_t)(cc * 2));
    bf16x4v hv;
    if (r < TOK) {
      const float4 v = *reinterpret_cast<const float4*>(xg + r * CDIM + cc);
      hv = (bf16x4v){(__bf16)v.x, (__bf16)v.y, (__bf16)v.z, (__bf16)v.w};
    } else {
      hv = (bf16x4v){(__bf16)0.f, (__bf16)0.f, (__bf16)0.f, (__bf16)0.f};
    }
    *reinterpret_cast<bf16x4v*>(smem + addr) = hv;
  }
  if (tid < 128) {
    // ones tile: 2048B = 128 x 16B. Row 0 (first 8 stores) = bf16(1.0), rest 0.
    uint4 fill = (tid < 8) ? make_uint4(0x3F803F80u, 0x3F803F80u, 0x3F803F80u, 0x3F803F80u)
                           : make_uint4(0u, 0u, 0u, 0u);
    *reinterpret_cast<uint4*>(smem + ONESOFF + (uint32_t)tid * 16u) = fill;
  }
  __syncthreads();

  // ---- Phase 2a: k (waves 0-5, swapped: k^T = W^T x^T -> packed stores) or
  //               v (waves 6-11, original orientation -> already packed) ----
  {
    const bool isv = wave >= 6;
    const int hw = isv ? wave - 6 : wave;          // head written
    if (isv) {
      const int ntg0 = 24 + 2 * hw;
#pragma unroll
      for (int i = 0; i < 2; ++i) {
        const int nt = ntg0 + i;
        const float bv = qkv_b[nt * 16 + l15];
        f32x4 acc[4];
#pragma unroll
        for (int m = 0; m < 4; ++m) acc[m] = (f32x4){bv, bv, bv, bv};
#pragma unroll
        for (int ks = 0; ks < 6; ++ks) {
          bf16x8 bf = *reinterpret_cast<const bf16x8*>(wqkv + ((size_t)(nt * 6 + ks) * 64 + lane) * 8);
#pragma unroll
          for (int m = 0; m < 4; ++m) {
            uint32_t row = (uint32_t)(m * 16 + l15);
            bf16x8 a = *reinterpret_cast<const bf16x8*>(smem + XOFF + row * 384u + swzA(row, (uint32_t)(ks * 64 + g16)));
            acc[m] = __builtin_amdgcn_mfma_f32_16x16x32_bf16(a, bf, acc[m], 0, 0, 0);
          }
        }
        const int d = (i << 4) + l15;
        uint32_t rowbase = VOFF + (uint32_t)hw * 4096u + (uint32_t)d * 128u;
#pragma unroll
        for (int m = 0; m < 4; ++m) {
          uint32_t c0 = (uint32_t)((m * 16 + rloc0) * 2);
          bf16x4v hv = (bf16x4v){(__bf16)acc[m][0], (__bf16)acc[m][1],
                                 (__bf16)acc[m][2], (__bf16)acc[m][3]};
          *reinterpret_cast<bf16x4v*>(smem + rowbase + swzA((uint32_t)d, c0)) = hv;
        }
      }
    } else {
      const int ntg0 = 12 + 2 * hw;
#pragma unroll
      for (int i = 0; i < 2; ++i) {
        const int nt = ntg0 + i;
        const float4 bv4 = *reinterpret_cast<const float4*>(qkv_b + nt * 16 + rloc0);
        f32x4 acc[4];   // k^T tiles: rows = d (i*16+rloc0+r), cols = tokens (m*16+l15)
#pragma unroll
        for (int m = 0; m < 4; ++m) acc[m] = (f32x4){bv4.x, bv4.y, bv4.z, bv4.w};
#pragma unroll
        for (int ks = 0; ks < 6; ++ks) {
          bf16x8 wf = *reinterpret_cast<const bf16x8*>(wqkv + ((size_t)(nt * 6 + ks) * 64 + lane) * 8);
#pragma unroll
          for (int m = 0; m < 4; ++m) {
            uint32_t row = (uint32_t)(m * 16 + l15);
            bf16x8 xf = *reinterpret_cast<const bf16x8*>(smem + XOFF + row * 384u + swzA(row, (uint32_t)(ks * 64 + g16)));
            acc[m] = __builtin_amdgcn_mfma_f32_16x16x32_bf16(wf, xf, acc[m], 0, 0, 0);
          }
        }
        // store k[tok][d]: row = tok (m*16+l15), 4 consecutive d -> packed 8B
        uint32_t cb = (uint32_t)((i * 16 + rloc0) * 2);
#pragma unroll
        for (int m = 0; m < 4; ++m) {
          uint32_t row = (uint32_t)(m * 16 + l15);
          bf16x4v hv = (bf16x4v){(__bf16)acc[m][0], (__bf16)acc[m][1],
                                 (__bf16)acc[m][2], (__bf16)acc[m][3]};
          *reinterpret_cast<bf16x4v*>(smem + KOFF + (uint32_t)hw * 4096u + row * 64u + swzQ(row, cb)) = hv;
        }
      }
    }
  }

  // ---- Phase 2b: q^T for own block (tokens 32*(wave&1)+0..31, ch 32h..32h+31) -> regs ----
  f32x4 qacc[2][2];   // [tok-tile][ch-tile]: rows = ch (n*16+rloc0+r), cols = tok
  {
#pragma unroll
    for (int n = 0; n < 2; ++n) {
      float4 bv4 = *reinterpret_cast<const float4*>(qkv_b + (2 * h + n) * 16 + rloc0);
      const float sc = QKSCALE * LOG2E;
      f32x4 bi = (f32x4){bv4.x * sc, bv4.y * sc, bv4.z * sc, bv4.w * sc};
      qacc[0][n] = bi;
      qacc[1][n] = bi;
    }
#pragma unroll
    for (int ks = 0; ks < 6; ++ks) {
      bf16x8 wf[2];
#pragma unroll
      for (int n = 0; n < 2; ++n)
        wf[n] = *reinterpret_cast<const bf16x8*>(wqkv + ((size_t)((2 * h + n) * 6 + ks) * 64 + lane) * 8);
#pragma unroll
      for (int tt = 0; tt < 2; ++tt) {
        uint32_t row = (uint32_t)((mbase + tt) * 16 + l15);
        bf16x8 xf = *reinterpret_cast<const bf16x8*>(smem + XOFF + row * 384u + swzA(row, (uint32_t)(ks * 64 + g16)));
#pragma unroll
        for (int n = 0; n < 2; ++n)
          qacc[tt][n] = __builtin_amdgcn_mfma_f32_16x16x32_bf16(wf[n], xf, qacc[tt][n], 0, 0, 0);
      }
    }
  }
  __syncthreads();   // x reads + k/v writes retire; x region becomes per-wave scratch

  const uint32_t sb = XOFF + (uint32_t)wave * 2048u;   // wave-private scratch
  const uint32_t vbase = VOFF + (uint32_t)h * 4096u;
  const uint32_t kbase = KOFF + (uint32_t)h * 4096u;

  // ---- q scatter: packed 8B stores into scratch [32 tok][32 ch] swzQ, then row reads ----
  bf16x8 qa0, qa1;
  {
#pragma unroll
    for (int tt = 0; tt < 2; ++tt)
#pragma unroll
      for (int n = 0; n < 2; ++n) {
        uint32_t row = (uint32_t)(tt * 16 + l15);
        uint32_t cb = (uint32_t)((n * 16 + rloc0) * 2);
        bf16x4v hv = (bf16x4v){(__bf16)qacc[tt][n][0], (__bf16)qacc[tt][n][1],
                               (__bf16)qacc[tt][n][2], (__bf16)qacc[tt][n][3]};
        *reinterpret_cast<bf16x4v*>(smem + sb + row * 64u + swzQ(row, cb)) = hv;
      }
    asm volatile("s_waitcnt lgkmcnt(0)" ::: "memory");
    qa0 = *reinterpret_cast<const bf16x8*>(smem + sb + (uint32_t)l15 * 64u + swzQ((uint32_t)l15, (uint32_t)g16));
    uint32_t r1 = (uint32_t)(l15 + 16);
    qa1 = *reinterpret_cast<const bf16x8*>(smem + sb + r1 * 64u + swzQ(r1, (uint32_t)g16));
  }

  bf16x4v p0[2];  // normalized t0 output (packed), held across the barrier

  // ---- t0: S^T = mfma(K, Q^T) -> exp2 -> P0 (own scratch, packed) -> o^T = mfma(V^T, P^T) ----
  {
    f32x4 s[4];
    const float* bt = bias_c + (size_t)((h * 4 + mbase) * 4 * 64 + lane) * 4;
#pragma unroll
    for (int nt = 0; nt < 4; ++nt)
      s[nt] = *reinterpret_cast<const f32x4*>(bt + (size_t)nt * 256);
#pragma unroll
    for (int nt = 0; nt < 4; ++nt) {
      uint32_t krow = (uint32_t)(nt * 16 + l15);
      bf16x8 kb = *reinterpret_cast<const bf16x8*>(smem + kbase + krow * 64u + swzQ(krow, (uint32_t)g16));
      s[nt] = __builtin_amdgcn_mfma_f32_16x16x32_bf16(kb, qa0, s[nt], 0, 0, 0);
    }
    // P0 = exp2(S^T): thread holds fixed qt=l15, 4 consecutive kt -> packed row store.
    // DS ops are in-order per wave, so these stores cannot bypass the qa reads above.
#pragma unroll
    for (int nt = 0; nt < 4; ++nt) {
      bf16x4v hv = (bf16x4v){(__bf16)exp2f(s[nt][0]), (__bf16)exp2f(s[nt][1]),
                             (__bf16)exp2f(s[nt][2]), (__bf16)exp2f(s[nt][3])};
      uint32_t cb = (uint32_t)((nt * 16 + rloc0) * 2);
      *reinterpret_cast<bf16x4v*>(smem + sb + (uint32_t)l15 * 128u + swzA((uint32_t)l15, cb)) = hv;
    }
    asm volatile("s_waitcnt lgkmcnt(0)" ::: "memory");
    f32x4 o[2], o2;
    o[0] = (f32x4){0.f, 0.f, 0.f, 0.f};
    o[1] = (f32x4){0.f, 0.f, 0.f, 0.f};
    o2 = (f32x4){0.f, 0.f, 0.f, 0.f};
#pragma unroll
    for (int ks = 0; ks < 2; ++ks) {
      bf16x8 pa = *reinterpret_cast<const bf16x8*>(smem + sb + (uint32_t)l15 * 128u + swzA((uint32_t)l15, (uint32_t)(ks * 64 + g16)));
#pragma unroll
      for (int n2 = 0; n2 < 2; ++n2) {
        uint32_t vrow = (uint32_t)(n2 * 16 + l15);
        bf16x8 vb = *reinterpret_cast<const bf16x8*>(smem + vbase + vrow * 128u + swzA(vrow, (uint32_t)(ks * 64 + g16)));
        o[n2] = __builtin_amdgcn_mfma_f32_16x16x32_bf16(vb, pa, o[n2], 0, 0, 0);
      }
      bf16x8 ob = *reinterpret_cast<const bf16x8*>(smem + ONESOFF + (uint32_t)l15 * 128u + swzA((uint32_t)l15, (uint32_t)(ks * 64 + g16)));
      o2 = __builtin_amdgcn_mfma_f32_16x16x32_bf16(ob, pa, o2, 0, 0, 0);
    }
    // row-sum for qt=l15 lives in o2[0] of lane l15 (grp 0)
    float is = __builtin_amdgcn_rcpf(__shfl(o2[0], l15));
#pragma unroll
    for (int n2 = 0; n2 < 2; ++n2)
      p0[n2] = (bf16x4v){(__bf16)(o[n2][0] * is), (__bf16)(o[n2][1] * is),
                         (__bf16)(o[n2][2] * is), (__bf16)(o[n2][3] * is)};
  }

  // ---- t1 S^T (k region still intact; all k reads complete before the barrier) ----
  f32x4 s1[4];
  {
    const float* bt = bias_c + (size_t)((h * 4 + mbase + 1) * 4 * 64 + lane) * 4;
#pragma unroll
    for (int nt = 0; nt < 4; ++nt)
      s1[nt] = *reinterpret_cast<const f32x4*>(bt + (size_t)nt * 256);
#pragma unroll
    for (int nt = 0; nt < 4; ++nt) {
      uint32_t krow = (uint32_t)(nt * 16 + l15);
      bf16x8 kb = *reinterpret_cast<const bf16x8*>(smem + kbase + krow * 64u + swzQ(krow, (uint32_t)g16));
      s1[nt] = __builtin_amdgcn_mfma_f32_16x16x32_bf16(kb, qa1, s1[nt], 0, 0, 0);
    }
  }
  __syncthreads();   // all k + scratch reads retire; k region -> P1, x region -> attn_o

  // ---- t1: exp2 -> P1 (k region wave slot) -> PV -> normalize ----
  bf16x4v p1[2];
  {
    const uint32_t pb1 = KOFF + (uint32_t)wave * 2048u;
#pragma unroll
    for (int nt = 0; nt < 4; ++nt) {
      bf16x4v hv = (bf16x4v){(__bf16)exp2f(s1[nt][0]), (__bf16)exp2f(s1[nt][1]),
                             (__bf16)exp2f(s1[nt][2]), (__bf16)exp2f(s1[nt][3])};
      uint32_t cb = (uint32_t)((nt * 16 + rloc0) * 2);
      *reinterpret_cast<bf16x4v*>(smem + pb1 + (uint32_t)l15 * 128u + swzA((uint32_t)l15, cb)) = hv;
    }
    asm volatile("s_waitcnt lgkmcnt(0)" ::: "memory");
    f32x4 o[2], o2;
    o[0] = (f32x4){0.f, 0.f, 0.f, 0.f};
    o[1] = (f32x4){0.f, 0.f, 0.f, 0.f};
    o2 = (f32x4){0.f, 0.f, 0.f, 0.f};
#pragma unroll
    for (int ks = 0; ks < 2; ++ks) {
      bf16x8 pa = *reinterpret_cast<const bf16x8*>(smem + pb1 + (uint32_t)l15 * 128u + swzA((uint32_t)l15, (uint32_t)(ks * 64 + g16)));
#pragma unroll
      for (int n2 = 0; n2 < 2; ++n2) {
        uint32_t vrow = (uint32_t)(n2 * 16 + l15);
        bf16x8 vb = *reinterpret_cast<const bf16x8*>(smem + vbase + vrow * 128u + swzA(vrow, (uint32_t)(ks * 64 + g16)));
        o[n2] = __builtin_amdgcn_mfma_f32_16x16x32_bf16(vb, pa, o[n2], 0, 0, 0);
      }
      bf16x8 ob = *reinterpret_cast<const bf16x8*>(smem + ONESOFF + (uint32_t)l15 * 128u + swzA((uint32_t)l15, (uint32_t)(ks * 64 + g16)));
      o2 = __builtin_amdgcn_mfma_f32_16x16x32_bf16(ob, pa, o2, 0, 0, 0);
    }
    float is = __builtin_amdgcn_rcpf(__shfl(o2[0], l15));
#pragma unroll
    for (int n2 = 0; n2 < 2; ++n2)
      p1[n2] = (bf16x4v){(__bf16)(o[n2][0] * is), (__bf16)(o[n2][1] * is),
                         (__bf16)(o[n2][2] * is), (__bf16)(o[n2][3] * is)};
  }

  // ---- attn_o writes for both tiles: o^T layout -> packed 8B row stores ----
  {
    uint32_t row0 = (uint32_t)(mbase * 16 + l15);
    uint32_t row1 = row0 + 16u;
#pragma unroll
    for (int n2 = 0; n2 < 2; ++n2) {
      uint32_t cb = (uint32_t)((h * 32 + n2 * 16 + rloc0) * 2);
      *reinterpret_cast<bf16x4v*>(smem + XOFF + row0 * 384u + swzA(row0, cb)) = p0[n2];
      *reinterpret_cast<bf16x4v*>(smem + XOFF + row1 * 384u + swzA(row1, cb)) = p1[n2];
    }
  }
  __syncthreads();

  // ---- Phase 4: proj. wave owns ntile=wave (cols 16w..16w+15), all 4 mtiles ----
  {
    const int ntp = wave;
    const float pb = proj_b[ntp * 16 + l15];
    f32x4 po[4];
#pragma unroll
    for (int m = 0; m < 4; ++m) po[m] = (f32x4){pb, pb, pb, pb};
#pragma unroll
    for (int ks = 0; ks < 6; ++ks) {
      bf16x8 bfp = *reinterpret_cast<const bf16x8*>(wproj + ((size_t)(ntp * 6 + ks) * 64 + lane) * 8);
#pragma unroll
      for (int m = 0; m < 4; ++m) {
        uint32_t row = (uint32_t)(m * 16 + l15);
        bf16x8 a = *reinterpret_cast<const bf16x8*>(smem + XOFF + row * 384u + swzA(row, (uint32_t)(ks * 64 + g16)));
        po[m] = __builtin_amdgcn_mfma_f32_16x16x32_bf16(a, bfp, po[m], 0, 0, 0);
      }
    }
    float* outg = out + (size_t)b * (TOK * CDIM);
    const int col = ntp * 16 + l15;
#pragma unroll
    for (int m = 0; m < 4; ++m)
#pragma unroll
      for (int r = 0; r < 4; ++r) {
        int row = m * 16 + rloc0 + r;
        if (row < TOK) outg[row * CDIM + col] = po[m][r];
      }
  }
}

extern "C" void kernel_launch(void* const* d_in, const int* in_sizes, int n_in,
                              void* d_out, int out_size, void* d_ws, size_t ws_size,
                              hipStream_t stream) {
  const float* x = (const float*)d_in[0];
  // d_in[1] = q_global : unused by the reference
  const float* qkv_w = (const float*)d_in[2];
  const float* qkv_b = (const float*)d_in[3];
  const float* proj_w = (const float*)d_in[4];
  const float* proj_b = (const float*)d_in[5];
  const float* rpb = (const float*)d_in[6];

  unsigned short* wqkv = (unsigned short*)d_ws;                 // 36*6*64*8 bf16 = 221184 B
  unsigned short* wproj = wqkv + (size_t)36 * 6 * 64 * 8;       // 12*6*64*8 bf16 = 73728 B
  float* bias_c = (float*)(wproj + (size_t)12 * 6 * 64 * 8);    // 6*4*4*64*4 f32 = 98304 B

  wa_pack_w<<<(36 * 6 * 64 + 255) / 256, 256, 0, stream>>>(qkv_w, wqkv, 36, 576, 12, QKSCALE * LOG2E);
  wa_pack_w<<<(12 * 6 * 64 + 255) / 256, 256, 0, stream>>>(proj_w, wproj, 12, 192, 0, 1.0f);
  wa_pack_bias<<<(NHEAD * 4 * 4 * 64 + 255) / 256, 256, 0, stream>>>(rpb, bias_c);

  hipFuncSetAttribute((const void*)wa_main, hipFuncAttributeMaxDynamicSharedMemorySize, (int)SMEM_BYTES);
  wa_main<<<2048, THREADS, SMEM_BYTES, stream>>>(x, qkv_b, proj_b, bias_c, wqkv, wproj, (float*)d_out);
}